// Round 9
// baseline (125.153 us; speedup 1.0000x reference)
//
#include <hip/hip_runtime.h>

#define NN 1024
#define FF 128

typedef __attribute__((ext_vector_type(8))) short bf16x8;
typedef __attribute__((ext_vector_type(4))) float f32x4;

__device__ __forceinline__ unsigned short f2bf(float x) {
  unsigned u = __float_as_uint(x);
  u += 0x7fff + ((u >> 16) & 1);   // round-to-nearest-even
  return (unsigned short)(u >> 16);
}
__device__ __forceinline__ float bf2f(unsigned short b) {
  return __uint_as_float(((unsigned)b) << 16);
}
__device__ __forceinline__ bf16x8 cvt8(float4 a, float4 b) {
  bf16x8 r;
  r[0] = (short)f2bf(a.x); r[1] = (short)f2bf(a.y);
  r[2] = (short)f2bf(a.z); r[3] = (short)f2bf(a.w);
  r[4] = (short)f2bf(b.x); r[5] = (short)f2bf(b.y);
  r[6] = (short)f2bf(b.z); r[7] = (short)f2bf(b.w);
  return r;
}

// async global->LDS, 16B per lane. LDS dest = wave-uniform base + lane*16.
__device__ __forceinline__ void gl_lds16(const void* g, void* l) {
  __builtin_amdgcn_global_load_lds(
      (const __attribute__((address_space(1))) unsigned*)g,
      (__attribute__((address_space(3))) unsigned*)l, 16, 0, 0);
}

// ---------------------------------------------------------------------------
// K1: deg[b,n] = 1 + sum_m A[b,n,m]; d = rsqrt(deg). One wave per row.
// Also writes Abf = bf16(A) so k_agg can double-buffer within 80KB LDS.
// Tail blocks (>=4096) build Wt[g][f] = bf16(W[f][g]).
// ---------------------------------------------------------------------------
__global__ __launch_bounds__(256) void k_deg(const float* __restrict__ A,
                                             const float* __restrict__ W,
                                             float* __restrict__ d,
                                             unsigned short* __restrict__ Wt,
                                             unsigned short* __restrict__ Abf) {
  if (blockIdx.x >= 4096) {
    int id = (blockIdx.x - 4096) * 256 + threadIdx.x;
    int g = id >> 7, f = id & 127;
    Wt[g * 128 + f] = f2bf(W[f * 128 + g]);
    return;
  }
  int row  = blockIdx.x * 4 + (threadIdx.x >> 6);
  int lane = threadIdx.x & 63;
  const float4* Ar = (const float4*)(A + (size_t)row * NN);
  unsigned short* Br = Abf + (size_t)row * NN;
  float s = 0.f;
#pragma unroll
  for (int i = 0; i < 4; ++i) {
    float4 v = Ar[lane + i * 64];
    ushort4 p; p.x = f2bf(v.x); p.y = f2bf(v.y); p.z = f2bf(v.z); p.w = f2bf(v.w);
    *(ushort4*)(Br + (lane + i * 64) * 4) = p;
    s += (v.x + v.y) + (v.z + v.w);
  }
#pragma unroll
  for (int off = 32; off > 0; off >>= 1) s += __shfl_down(s, off, 64);
  if (lane == 0) d[row] = rsqrtf(s + 1.0f);
}

// ---------------------------------------------------------------------------
// K2: Yt[b][g][m] = bf16( d[b,m] * sum_f X[b,m,f] * W[f,g] )
// LDS-staged, single K-stage (K=128). Block: 64 m-rows x 128 g, 4 waves.
// XOR-swizzled LDS (16B chunks): row r, chunk c stored at pos c^(r&15).
// ---------------------------------------------------------------------------
__global__ __launch_bounds__(256) void k_xw(const float* __restrict__ X,
                                            const unsigned short* __restrict__ Wt,
                                            const float* __restrict__ d,
                                            unsigned short* __restrict__ Yt) {
  __shared__ __align__(16) unsigned short Xs[64 * 128];
  __shared__ __align__(16) unsigned short Ws[128 * 128];
  __shared__ float dl[64];
  int t  = threadIdx.x;
  int b  = blockIdx.x >> 4;
  int m0 = (blockIdx.x & 15) * 64;

#pragma unroll
  for (int j = 0; j < 4; ++j) {
    int id = t + j * 256;
    int r = id >> 4, p = id & 15, c = p ^ (r & 15);
    const float* gp = X + ((size_t)(b * NN + m0 + r) * FF + c * 8);
    float4 v0 = *(const float4*)gp;
    float4 v1 = *(const float4*)(gp + 4);
    *(bf16x8*)&Xs[r * 128 + p * 8] = cvt8(v0, v1);
  }
#pragma unroll
  for (int j = 0; j < 8; ++j) {
    int id = t + j * 256;
    int g = id >> 4, p = id & 15, c = p ^ (g & 15);
    uint4 v = *(const uint4*)(Wt + g * 128 + c * 8);
    *(uint4*)&Ws[g * 128 + p * 8] = v;
  }
  if (t < 64) dl[t] = d[b * NN + m0 + t];
  __syncthreads();

  int wave = t >> 6, lane = t & 63, quad = lane >> 4, l16 = lane & 15;
  f32x4 acc[8];
#pragma unroll
  for (int ct = 0; ct < 8; ++ct) acc[ct] = (f32x4){0.f, 0.f, 0.f, 0.f};

#pragma unroll
  for (int ks = 0; ks < 4; ++ks) {
    int q = ks * 4 + quad;
    bf16x8 a = *(const bf16x8*)&Xs[(wave * 16 + l16) * 128 + (q ^ l16) * 8];
#pragma unroll
    for (int ct = 0; ct < 8; ++ct) {
      bf16x8 w = *(const bf16x8*)&Ws[(ct * 16 + l16) * 128 + (q ^ l16) * 8];
      acc[ct] = __builtin_amdgcn_mfma_f32_16x16x32_bf16(a, w, acc[ct], 0, 0, 0);
    }
  }

  int mb = wave * 16 + quad * 4;
  float4 d4 = *(const float4*)&dl[mb];
#pragma unroll
  for (int ct = 0; ct < 8; ++ct) {
    int g = ct * 16 + l16;
    ushort4 p;
    p.x = f2bf(d4.x * acc[ct][0]);
    p.y = f2bf(d4.y * acc[ct][1]);
    p.z = f2bf(d4.z * acc[ct][2]);
    p.w = f2bf(d4.w * acc[ct][3]);
    *(ushort4*)(Yt + (size_t)(b * 128 + g) * NN + m0 + mb) = p;
  }
}

// ---------------------------------------------------------------------------
// K3: out[b,n,g] = d[n] * ( sum_m Abf[b,n,m]*Yt[b,g,m] + Yt[b,g,n] )
// Per-batch GEMM 1024x128x1024, A as bf16 (Abf, L3-resident). BM=32, BN=128,
// BK=128, 8 stages, DOUBLE-buffered LDS: 2 x (A 8KB + Y 32KB) = 80KB
// -> 2 blocks/CU. One barrier per stage; stage s+1's global_load_lds issued
// right after the barrier, in flight across all of stage-s compute — the
// structural vmcnt(0) drain at the next barrier is mostly pre-covered.
// XCD swizzle: bid&7 selects XCD; 2 batches/XCD -> Yt (512KB) L2-resident.
// ---------------------------------------------------------------------------
__global__ __launch_bounds__(256) void k_agg(const unsigned short* __restrict__ Abf,
                                             const unsigned short* __restrict__ Yt,
                                             const float* __restrict__ d,
                                             float* __restrict__ out) {
  __shared__ __align__(16) unsigned short As[2][32 * 128];
  __shared__ __align__(16) unsigned short Ys[2][128 * 128];
  int t   = threadIdx.x;
  int bid = blockIdx.x;
  int xcd = bid & 7;
  int j   = bid >> 3;                    // 0..63
  int b   = xcd + 8 * (j >> 5);          // all 32 blocks of batch b on one XCD
  int n0  = (j & 31) * 32;
  int wave = t >> 6, lane = t & 63, quad = lane >> 4, l16 = lane & 15;
  int wr = wave >> 1, wc = wave & 1;
  int rl = lane >> 4, pl = lane & 15;    // staging: row-within-4, chunk pos

  const unsigned short* Ab = Abf + (size_t)(b * NN + n0) * NN;
  const unsigned short* Yb = Yt + (size_t)b * 128 * NN;

  auto issue = [&](int k0, int buf) {
#pragma unroll
    for (int jj = 0; jj < 2; ++jj) {     // A: 32 rows x 256B bf16
      int r0 = wave * 8 + jj * 4;
      int r  = r0 + rl;
      int c  = pl ^ (r & 15);
      gl_lds16(Ab + ((size_t)r * NN + k0 + c * 8), &As[buf][r0 * 128]);
    }
#pragma unroll
    for (int jj = 0; jj < 8; ++jj) {     // Y: 128 rows x 256B bf16
      int r0 = wave * 32 + jj * 4;
      int r  = r0 + rl;
      int c  = pl ^ (r & 15);
      gl_lds16(Yb + ((size_t)r * NN + k0 + c * 8), &Ys[buf][r0 * 128]);
    }
  };

  f32x4 acc[4];
#pragma unroll
  for (int ct = 0; ct < 4; ++ct) acc[ct] = (f32x4){0.f, 0.f, 0.f, 0.f};

  issue(0, 0);
  for (int s = 0; s < 8; ++s) {
    int cur = s & 1;
    __syncthreads();                     // stage-s data in LDS; prev reads done
    if (s < 7) issue((s + 1) * 128, cur ^ 1);   // fly across stage-s compute
#pragma unroll
    for (int ks = 0; ks < 4; ++ks) {
      int cq = ks * 4 + quad;
      bf16x8 a = *(const bf16x8*)&As[cur][(wr * 16 + l16) * 128 + (cq ^ l16) * 8];
#pragma unroll
      for (int ct = 0; ct < 4; ++ct) {
        bf16x8 y = *(const bf16x8*)&Ys[cur][(wc * 64 + ct * 16 + l16) * 128 + (cq ^ l16) * 8];
        acc[ct] = __builtin_amdgcn_mfma_f32_16x16x32_bf16(a, y, acc[ct], 0, 0, 0);
      }
    }
  }

  // epilogue: out[n,g] = d[n]*(acc + Yt[g][n]); C/D: row = quad*4+reg, col = l16
  int nb = n0 + wr * 16 + quad * 4;
  float4 d4 = *(const float4*)(d + b * NN + nb);
#pragma unroll
  for (int ct = 0; ct < 4; ++ct) {
    int g = wc * 64 + ct * 16 + l16;
    ushort4 yv = *(const ushort4*)(Yt + (size_t)(b * 128 + g) * NN + nb);
    float* op = out + ((size_t)(b * NN + nb) * FF + g);
    op[0 * FF] = d4.x * (acc[ct][0] + bf2f(yv.x));
    op[1 * FF] = d4.y * (acc[ct][1] + bf2f(yv.y));
    op[2 * FF] = d4.z * (acc[ct][2] + bf2f(yv.z));
    op[3 * FF] = d4.w * (acc[ct][3] + bf2f(yv.w));
  }
}

// ---------------------------------------------------------------------------
extern "C" void kernel_launch(void* const* d_in, const int* in_sizes, int n_in,
                              void* d_out, int out_size, void* d_ws, size_t ws_size,
                              hipStream_t stream) {
  const float* X = (const float*)d_in[0];  // [16,1024,128]
  const float* A = (const float*)d_in[1];  // [16,1024,1024]
  const float* W = (const float*)d_in[2];  // [128,128]
  float* out = (float*)d_out;              // [16,1024,128]

  char* ws = (char*)d_ws;
  float*          dinv = (float*)ws;                              // 64 KB
  unsigned short* Wt   = (unsigned short*)(ws + 65536);           // 32 KB
  unsigned short* Yt   = (unsigned short*)(ws + 98304);           // 4 MB [b][g][m]
  unsigned short* Abf  = (unsigned short*)(ws + 98304 + 4194304); // 32 MB bf16(A)

  k_deg<<<dim3(4096 + 64), dim3(256), 0, stream>>>(A, W, dinv, Wt, Abf);
  k_xw <<<dim3(256),       dim3(256), 0, stream>>>(X, Wt, dinv, Yt);
  k_agg<<<dim3(512),       dim3(256), 0, stream>>>(Abf, Yt, dinv, out);
}

// Round 10
// 122.933 us; speedup vs baseline: 1.0181x; 1.0181x over previous
//
#include <hip/hip_runtime.h>

#define NN 1024
#define FF 128

typedef __attribute__((ext_vector_type(8))) short bf16x8;
typedef __attribute__((ext_vector_type(4))) float f32x4;

__device__ __forceinline__ unsigned short f2bf(float x) {
  unsigned u = __float_as_uint(x);
  u += 0x7fff + ((u >> 16) & 1);   // round-to-nearest-even
  return (unsigned short)(u >> 16);
}
__device__ __forceinline__ float bf2f(unsigned short b) {
  return __uint_as_float(((unsigned)b) << 16);
}
__device__ __forceinline__ bf16x8 cvt8(float4 a, float4 b) {
  bf16x8 r;
  r[0] = (short)f2bf(a.x); r[1] = (short)f2bf(a.y);
  r[2] = (short)f2bf(a.z); r[3] = (short)f2bf(a.w);
  r[4] = (short)f2bf(b.x); r[5] = (short)f2bf(b.y);
  r[6] = (short)f2bf(b.z); r[7] = (short)f2bf(b.w);
  return r;
}

// async global->LDS, 16B per lane. LDS dest = wave-uniform base + lane*16.
__device__ __forceinline__ void gl_lds16(const void* g, void* l) {
  __builtin_amdgcn_global_load_lds(
      (const __attribute__((address_space(1))) unsigned*)g,
      (__attribute__((address_space(3))) unsigned*)l, 16, 0, 0);
}

// ---------------------------------------------------------------------------
// K1 (fused): blocks [0,256) compute UNSCALED Yt[b][g][m] = bf16((XW)[m,g])
// (no d dependency — W transposed per-block into LDS from global W);
// blocks [256,4352) compute deg rows: d = rsqrt(1 + rowsum(A)), pure read,
// leaving A L3-resident for k_agg. xw blocks dispatch FIRST so their ~3us
// hides entirely under the 4096-block deg memory stream.
// XOR-swizzled LDS (16B chunks): row r, chunk c stored at pos c^(r&15).
// ---------------------------------------------------------------------------
__global__ __launch_bounds__(256) void k_pre(const float* __restrict__ A,
                                             const float* __restrict__ X,
                                             const float* __restrict__ W,
                                             float* __restrict__ d,
                                             unsigned short* __restrict__ Yt) {
  __shared__ __align__(16) unsigned short Xs[64 * 128];   // 16 KB
  __shared__ __align__(16) unsigned short Wl[128 * 128];  // 32 KB
  int t = threadIdx.x;
  int wave = t >> 6, lane = t & 63;

  if (blockIdx.x >= 256) {
    // ---- deg branch: one wave per row ----
    int row = (blockIdx.x - 256) * 4 + wave;
    const float4* Ar = (const float4*)(A + (size_t)row * NN);
    float s = 0.f;
#pragma unroll
    for (int i = 0; i < 4; ++i) {
      float4 v = Ar[lane + i * 64];
      s += (v.x + v.y) + (v.z + v.w);
    }
#pragma unroll
    for (int off = 32; off > 0; off >>= 1) s += __shfl_down(s, off, 64);
    if (lane == 0) d[row] = rsqrtf(s + 1.0f);
    return;
  }

  // ---- xw branch: block = 64 m-rows x 128 g of one batch ----
  int b  = blockIdx.x >> 4;
  int m0 = (blockIdx.x & 15) * 64;

  // stage X tile (64x128 fp32 -> bf16, swizzled)
#pragma unroll
  for (int j = 0; j < 4; ++j) {
    int id = t + j * 256;
    int r = id >> 4, p = id & 15, c = p ^ (r & 15);
    const float* gp = X + ((size_t)(b * NN + m0 + r) * FF + c * 8);
    float4 v0 = *(const float4*)gp;
    float4 v1 = *(const float4*)(gp + 4);
    *(bf16x8*)&Xs[r * 128 + p * 8] = cvt8(v0, v1);
  }
  // stage W transposed: W[f][g] -> Wl[g][pos(f)], coalesced read, scatter write
#pragma unroll
  for (int j = 0; j < 16; ++j) {
    int id4 = t + j * 256;               // 0..4095 float4s of W
    int f = id4 >> 5, g4 = (id4 & 31) * 4;
    float4 v = *(const float4*)(W + f * 128 + g4);
    unsigned short pv[4];
    pv[0] = f2bf(v.x); pv[1] = f2bf(v.y); pv[2] = f2bf(v.z); pv[3] = f2bf(v.w);
#pragma unroll
    for (int i = 0; i < 4; ++i) {
      int g = g4 + i;
      Wl[g * 128 + (((f >> 3) ^ (g & 15)) << 3) + (f & 7)] = pv[i];
    }
  }
  __syncthreads();

  int quad = lane >> 4, l16 = lane & 15;
  f32x4 acc[8];
#pragma unroll
  for (int ct = 0; ct < 8; ++ct) acc[ct] = (f32x4){0.f, 0.f, 0.f, 0.f};

#pragma unroll
  for (int ks = 0; ks < 4; ++ks) {
    int q = ks * 4 + quad;
    bf16x8 a = *(const bf16x8*)&Xs[(wave * 16 + l16) * 128 + (q ^ l16) * 8];
#pragma unroll
    for (int ct = 0; ct < 8; ++ct) {
      bf16x8 w = *(const bf16x8*)&Wl[(ct * 16 + l16) * 128 + (q ^ l16) * 8];
      acc[ct] = __builtin_amdgcn_mfma_f32_16x16x32_bf16(a, w, acc[ct], 0, 0, 0);
    }
  }

  // store UNSCALED, transposed: Yt[b][g][m]; C/D: row(m)=quad*4+reg, col(g)=l16
  int mb = wave * 16 + quad * 4;
#pragma unroll
  for (int ct = 0; ct < 8; ++ct) {
    int g = ct * 16 + l16;
    ushort4 p;
    p.x = f2bf(acc[ct][0]);
    p.y = f2bf(acc[ct][1]);
    p.z = f2bf(acc[ct][2]);
    p.w = f2bf(acc[ct][3]);
    *(ushort4*)(Yt + (size_t)(b * 128 + g) * NN + m0 + mb) = p;
  }
}

// ---------------------------------------------------------------------------
// K2: out[n,g] = d[n] * ( sum_m A[n,m]*d[m]*Y[m,g] + d[n]*Y[n,g] )
// Per-batch GEMM 1024x128x1024, A read as RAW FP32 (L3-resident after k_pre).
// R7 structure: BM=32, BN=128, BK=128, 8 stages, single LDS buffer
// (A fp32 16KB + Y bf16 32KB + d 4KB = 52KB -> 3 blocks/CU capacity; grid 512
// -> 2 resident/CU, TLP hides the vmcnt(0) barrier drain). d[m] folded into
// the existing fp32->bf16 A-conversion (broadcast LDS reads per quad).
// XCD swizzle: bid&7 selects XCD; 2 batches/XCD -> Yt (512KB) L2-resident.
// ---------------------------------------------------------------------------
__global__ __launch_bounds__(256) void k_agg(const float* __restrict__ A,
                                             const unsigned short* __restrict__ Yt,
                                             const float* __restrict__ d,
                                             float* __restrict__ out) {
  __shared__ __align__(16) float          Asf[32 * 128];      // fp32 A tile
  __shared__ __align__(16) unsigned short Ys[128 * 128];      // bf16 Y tile
  __shared__ __align__(16) float          dl[NN];             // whole batch d
  int t   = threadIdx.x;
  int bid = blockIdx.x;
  int xcd = bid & 7;
  int j   = bid >> 3;                    // 0..63
  int b   = xcd + 8 * (j >> 5);          // all 32 blocks of batch b on one XCD
  int n0  = (j & 31) * 32;
  int wave = t >> 6, lane = t & 63, quad = lane >> 4, l16 = lane & 15;
  int wr = wave >> 1, wc = wave & 1;
  int rl = lane >> 4, pl = lane & 15;   // Y staging: row-within-4, chunk pos
  int rh = lane >> 5, cc = lane & 31;   // A staging: row-within-2, chunk pos

  const float*          Ab = A  + (size_t)(b * NN + n0) * NN;
  const unsigned short* Yb = Yt + (size_t)b * 128 * NN;

  // stage whole batch's d (1024 floats) once
  *(float4*)&dl[t * 4] = *(const float4*)(d + (size_t)b * NN + t * 4);

  auto issue = [&](int k0) {
#pragma unroll
    for (int jj = 0; jj < 4; ++jj) {     // A: 32 rows x 512B fp32
      int r0 = wave * 8 + jj * 2;
      int r  = r0 + rh;
      int c  = cc ^ (2 * (r & 15));
      gl_lds16(Ab + ((size_t)r * NN + k0 + c * 4), &Asf[r0 * 128]);
    }
#pragma unroll
    for (int jj = 0; jj < 8; ++jj) {     // Y: 128 rows x 256B bf16
      int r0 = wave * 32 + jj * 4;
      int r  = r0 + rl;
      int c  = pl ^ (r & 15);
      gl_lds16(Yb + ((size_t)r * NN + k0 + c * 8), &Ys[r0 * 128]);
    }
  };

  f32x4 acc[4];
#pragma unroll
  for (int ct = 0; ct < 4; ++ct) acc[ct] = (f32x4){0.f, 0.f, 0.f, 0.f};

  const float4* dl4 = (const float4*)dl;
  int swA = 2 * l16;                     // even XOR for A-frag positions
  issue(0);
  for (int s = 0; s < 8; ++s) {
    __syncthreads();                     // stage-s data (and dl) in LDS
#pragma unroll
    for (int ks = 0; ks < 4; ++ks) {
      int cq = ks * 4 + quad;
      int pa = (2 * cq) ^ swA;           // chunk pos of 8-float fragment
      float4 a0 = *(const float4*)&Asf[(wr * 16 + l16) * 128 + pa * 4];
      float4 a1 = *(const float4*)&Asf[(wr * 16 + l16) * 128 + pa * 4 + 4];
      float4 dm0 = dl4[s * 32 + cq * 2];       // d[m] for k = s*128+cq*8 ..+3
      float4 dm1 = dl4[s * 32 + cq * 2 + 1];   // ..+4..+7 (quad-broadcast)
      a0.x *= dm0.x; a0.y *= dm0.y; a0.z *= dm0.z; a0.w *= dm0.w;
      a1.x *= dm1.x; a1.y *= dm1.y; a1.z *= dm1.z; a1.w *= dm1.w;
      bf16x8 a = cvt8(a0, a1);
#pragma unroll
      for (int ct = 0; ct < 4; ++ct) {
        bf16x8 y = *(const bf16x8*)&Ys[(wc * 64 + ct * 16 + l16) * 128 + (cq ^ l16) * 8];
        acc[ct] = __builtin_amdgcn_mfma_f32_16x16x32_bf16(a, y, acc[ct], 0, 0, 0);
      }
    }
    __syncthreads();                     // all waves done reading stage s
    if (s < 7) issue((s + 1) * 128);
  }

  // epilogue: out[n,g] = d[n]*(acc + d[n]*Y[n,g]); C/D: row=quad*4+reg, col=l16
  int nb = n0 + wr * 16 + quad * 4;
  float4 d4 = dl4[nb >> 2];
#pragma unroll
  for (int ct = 0; ct < 4; ++ct) {
    int g = wc * 64 + ct * 16 + l16;
    ushort4 yv = *(const ushort4*)(Yt + (size_t)(b * 128 + g) * NN + nb);
    float* op = out + ((size_t)(b * NN + nb) * FF + g);
    op[0 * FF] = d4.x * (acc[ct][0] + d4.x * bf2f(yv.x));
    op[1 * FF] = d4.y * (acc[ct][1] + d4.y * bf2f(yv.y));
    op[2 * FF] = d4.z * (acc[ct][2] + d4.z * bf2f(yv.z));
    op[3 * FF] = d4.w * (acc[ct][3] + d4.w * bf2f(yv.w));
  }
}

// ---------------------------------------------------------------------------
extern "C" void kernel_launch(void* const* d_in, const int* in_sizes, int n_in,
                              void* d_out, int out_size, void* d_ws, size_t ws_size,
                              hipStream_t stream) {
  const float* X = (const float*)d_in[0];  // [16,1024,128]
  const float* A = (const float*)d_in[1];  // [16,1024,1024]
  const float* W = (const float*)d_in[2];  // [128,128]
  float* out = (float*)d_out;              // [16,1024,128]

  char* ws = (char*)d_ws;
  float*          dinv = (float*)ws;                    // 64 KB
  unsigned short* Yt   = (unsigned short*)(ws + 65536); // 4 MB [b][g][m], UNSCALED

  k_pre<<<dim3(256 + 4096), dim3(256), 0, stream>>>(A, X, W, dinv, Yt);
  k_agg<<<dim3(512),        dim3(256), 0, stream>>>(A, Yt, dinv, out);
}